// Round 1
// baseline (233.383 us; speedup 1.0000x reference)
//
#include <hip/hip_runtime.h>

typedef __bf16 bf16x8 __attribute__((ext_vector_type(8)));
typedef float f32x4 __attribute__((ext_vector_type(4)));

#define B_ 16
#define T_ 1024
#define D_ 512
#define S_ 12
#define C_ 11
static constexpr int P_TOTAL = 2148960;  // 176 * (12*1024 - 78)

__device__ __host__ inline constexpr int pred_base(int i) {
  return C_ * B_ * (T_ * i - (i * (i + 1)) / 2);
}

__device__ inline unsigned short f2bf(float f) {
  unsigned int u = __float_as_uint(f);
  u += 0x7FFF + ((u >> 16) & 1);   // round-to-nearest-even
  return (unsigned short)(u >> 16);
}

__device__ inline void gld16(const void* g, void* l) {
  __builtin_amdgcn_global_load_lds(
      (const __attribute__((address_space(1))) void*)g,
      (__attribute__((address_space(3))) void*)l, 16, 0, 0);
}

// ---------------- prep: W [i][o][s] f32 -> wt [s][o][i] bf16 ----------------
__global__ __launch_bounds__(256) void prep_w(const float* __restrict__ W,
                                              unsigned short* __restrict__ wt) {
  __shared__ unsigned short tile[32][33][12];   // padded: ii-stride 396 shorts
  const int i0 = blockIdx.x * 32, o0 = blockIdx.y * 32;
#pragma unroll
  for (int q = 0; q < 48; ++q) {
    int idx = threadIdx.x + q * 256;            // 12288 elements
    int ii = idx / 384, rem = idx % 384;
    int oo = rem / 12, ss = rem % 12;
    tile[ii][oo][ss] = f2bf(W[(size_t)(i0 + ii) * 6144 + (size_t)o0 * 12 + rem]);
  }
  __syncthreads();
#pragma unroll
  for (int q = 0; q < 48; ++q) {
    int idx = threadIdx.x + q * 256;
    int ss = idx / 1024, rem = idx % 1024;
    int oo = rem / 32, ii = rem % 32;
    wt[(size_t)ss * (D_ * D_) + (size_t)(o0 + oo) * D_ + (i0 + ii)] = tile[ii][oo][ss];
  }
}

// ------- prep: transpose [b][D][T] f32 -> [b][T][D] bf16 (x->xb, y->yT) -----
__global__ __launch_bounds__(256) void prep_t(const float* __restrict__ in,
                                              unsigned short* __restrict__ ob) {
  __shared__ float tile[32][33];
  const int t0 = blockIdx.x * 32;
  const int d0 = blockIdx.y * 32;
  const int b = blockIdx.z;
  const float* ib = in + (size_t)b * D_ * T_;
  const int r = threadIdx.x / 32, c = threadIdx.x % 32;
#pragma unroll
  for (int p = 0; p < 4; ++p) {
    int rr = r + p * 8;
    tile[rr][c] = ib[(size_t)(d0 + rr) * T_ + t0 + c];
  }
  __syncthreads();
  unsigned short* op = ob + (size_t)b * T_ * D_;
#pragma unroll
  for (int p = 0; p < 4; ++p) {
    int rr = r + p * 8;
    op[(size_t)(t0 + rr) * D_ + d0 + c] = f2bf(tile[c][rr]);
  }
}

// ---------------- labels: out[P_TOTAL + k] ----------------
__global__ void labels_k(float* __restrict__ lab) {
  int k = blockIdx.x * 256 + threadIdx.x;
  if (k >= P_TOTAL) return;
  int i = 0;
#pragma unroll
  for (int q = 1; q < 12; ++q)
    if (k >= pred_base(q)) i = q;
  int rel = k - pred_base(i);
  int len = T_ - 1 - i;
  lab[k] = (rel < B_ * len) ? 1.0f : 0.0f;
}

// ---- GEMM: xp[bl][s][t][o] (bf16) = xb[m][i] * wt[s][o][i] + bias[o] -------
// 128x128 tile, BK=32, 4 waves, m97-style global_load_lds double-buffer.
__global__ __launch_bounds__(256) void gemm_xp(
    const unsigned short* __restrict__ xb,   // [16384][512]
    const unsigned short* __restrict__ wt,   // [12][512 o][512 i]
    const float* __restrict__ bias,          // [512]
    unsigned short* __restrict__ xp,         // [nb][12][1024][512]
    int m0_global) {
  __shared__ unsigned short lA[2][128 * 32];
  __shared__ unsigned short lB[2][128 * 32];
  const int tid = threadIdx.x;
  const int s = blockIdx.z;
  const int n0 = blockIdx.y * 128;
  const int ml0 = blockIdx.x * 128;
  const unsigned short* Ag = xb + (size_t)(m0_global + ml0) * D_;
  const unsigned short* Bg = wt + ((size_t)s * D_ + n0) * D_;

  auto stage = [&](int buf, int kt) {
#pragma unroll
    for (int q = 0; q < 2; ++q) {
      int o2 = tid * 16 + q * 4096;           // byte offset in 8KB tile
      int row = o2 >> 6;                      // 64B (32 bf16) per row
      int colb = o2 & 63;
      gld16((const char*)Ag + (size_t)row * (D_ * 2) + kt * 64 + colb,
            (char*)(&lA[buf][0]) + o2);
      gld16((const char*)Bg + (size_t)row * (D_ * 2) + kt * 64 + colb,
            (char*)(&lB[buf][0]) + o2);
    }
  };

  const int w = tid >> 6, l = tid & 63;
  const int wm = (w >> 1) * 64, wn = (w & 1) * 64;
  const int fr = l & 15, koff = (l >> 4) * 8;

  f32x4 acc[4][4];
#pragma unroll
  for (int ia = 0; ia < 4; ++ia)
#pragma unroll
    for (int ib = 0; ib < 4; ++ib)
#pragma unroll
      for (int e = 0; e < 4; ++e) acc[ia][ib][e] = 0.f;

  stage(0, 0);
  asm volatile("s_waitcnt vmcnt(0)" ::: "memory");
  __syncthreads();

  for (int kt = 0; kt < 16; ++kt) {
    int cur = kt & 1;
    if (kt + 1 < 16) stage(cur ^ 1, kt + 1);
    bf16x8 af[4], bfr[4];
#pragma unroll
    for (int fm = 0; fm < 4; ++fm)
      af[fm] = *(const bf16x8*)&lA[cur][(wm + fm * 16 + fr) * 32 + koff];
#pragma unroll
    for (int fn = 0; fn < 4; ++fn)
      bfr[fn] = *(const bf16x8*)&lB[cur][(wn + fn * 16 + fr) * 32 + koff];
#pragma unroll
    for (int fm = 0; fm < 4; ++fm)
#pragma unroll
      for (int fn = 0; fn < 4; ++fn)
        acc[fm][fn] = __builtin_amdgcn_mfma_f32_16x16x32_bf16(
            af[fm], bfr[fn], acc[fm][fn], 0, 0, 0);
    asm volatile("s_waitcnt vmcnt(0)" ::: "memory");
    __syncthreads();
  }

  float bv[4];
#pragma unroll
  for (int fn = 0; fn < 4; ++fn) bv[fn] = bias[n0 + wn + fn * 16 + fr];

#pragma unroll
  for (int fm = 0; fm < 4; ++fm) {
#pragma unroll
    for (int r = 0; r < 4; ++r) {
      int m = ml0 + wm + fm * 16 + (l >> 4) * 4 + r;   // local row in chunk
      int bl = m >> 10, t = m & 1023;
      size_t orow = (((size_t)bl * S_ + s) * T_ + t) * D_;
#pragma unroll
      for (int fn = 0; fn < 4; ++fn) {
        int o = n0 + wn + fn * 16 + fr;
        xp[orow + o] = f2bf(acc[fm][fn][r] + bv[fn]);
      }
    }
  }
}

// ---- predictions: one wave per (b, tt); 12x11 tile of dots via 16 MFMAs ----
// p[i(row), c(col)] = sum_f xp[bl][i][tt-1-i][f] * yT[b][j(c,tt)][f]
__global__ __launch_bounds__(256) void pred_k(
    const unsigned short* __restrict__ xp,   // [nb][12][1024][512]
    const unsigned short* __restrict__ yT,   // [16][1024][512]
    const int* __restrict__ negs,            // [16][10][1024]
    float* __restrict__ preds, int b0) {
  const int w = threadIdx.x >> 6, l = threadIdx.x & 63;
  const int tt = blockIdx.x * 4 + w;
  const int bl = blockIdx.y;
  const int b = b0 + bl;
  if (tt < 1 || tt >= T_) return;

  const int fr = l & 15;
  const int koff = (l >> 4) * 8;

  // A operand row (i = fr): clamp invalid rows to a safe valid address;
  // their outputs are never stored, and MFMA elements are independent.
  int t = tt - 1 - fr;
  bool av = (fr < S_) && (t >= 0);
  int si = av ? fr : 0;
  int st = av ? t : 0;
  const unsigned short* arow = xp + (((size_t)bl * S_ + si) * T_ + st) * D_;

  // B operand col (c = fr): c==0 -> y column tt; 1..10 -> gathered neg column.
  int j = tt;
  if (fr >= 1 && fr <= 10) j = negs[b * (10 * T_) + (fr - 1) * T_ + tt];
  const unsigned short* brow = yT + ((size_t)b * T_ + j) * D_;

  f32x4 acc;
#pragma unroll
  for (int e = 0; e < 4; ++e) acc[e] = 0.f;
#pragma unroll
  for (int kk = 0; kk < 16; ++kk) {
    bf16x8 a = *(const bf16x8*)(arow + kk * 32 + koff);
    bf16x8 bb = *(const bf16x8*)(brow + kk * 32 + koff);
    acc = __builtin_amdgcn_mfma_f32_16x16x32_bf16(a, bb, acc, 0, 0, 0);
  }
#pragma unroll
  for (int r = 0; r < 4; ++r) {
    int ii = (l >> 4) * 4 + r;
    int to = tt - 1 - ii;
    if (ii < S_ && fr < C_ && to >= 0) {
      int len = T_ - 1 - ii;
      preds[pred_base(ii) + ((size_t)fr * B_ + b) * len + to] = acc[r];
    }
  }
}

extern "C" void kernel_launch(void* const* d_in, const int* in_sizes, int n_in,
                              void* d_out, int out_size, void* d_ws, size_t ws_size,
                              hipStream_t stream) {
  (void)in_sizes; (void)n_in; (void)out_size;
  const float* x = (const float*)d_in[0];
  const float* y = (const float*)d_in[1];
  const float* W = (const float*)d_in[2];
  const float* bias = (const float*)d_in[3];
  const int* negs = (const int*)d_in[4];
  float* out = (float*)d_out;
  char* ws = (char*)d_ws;

  unsigned short* wt = (unsigned short*)ws;                         // 6,291,456 B
  unsigned short* xb = (unsigned short*)(ws + 6291456);             // 16,777,216 B
  unsigned short* yT = (unsigned short*)(ws + 6291456 + 16777216);  // 16,777,216 B
  unsigned short* xp = (unsigned short*)(ws + 6291456 + 2 * 16777216);
  const size_t fixed = 6291456 + (size_t)2 * 16777216;              // 39,845,888
  const size_t xp_per_b = (size_t)S_ * T_ * D_ * 2;                 // 12,582,912
  int nb = 1;
  if (ws_size > fixed) {
    size_t cap = (ws_size - fixed) / xp_per_b;
    nb = cap < 1 ? 1 : (cap > 16 ? 16 : (int)cap);
  }

  hipLaunchKernelGGL(prep_w, dim3(16, 16), dim3(256), 0, stream, W, wt);
  hipLaunchKernelGGL(prep_t, dim3(32, 16, 16), dim3(256), 0, stream, x, xb);
  hipLaunchKernelGGL(prep_t, dim3(32, 16, 16), dim3(256), 0, stream, y, yT);
  hipLaunchKernelGGL(labels_k, dim3((P_TOTAL + 255) / 256), dim3(256), 0, stream,
                     out + P_TOTAL);

  for (int b0 = 0; b0 < B_; b0 += nb) {
    int bc = (B_ - b0) < nb ? (B_ - b0) : nb;
    hipLaunchKernelGGL(gemm_xp, dim3(bc * 8, 4, 12), dim3(256), 0, stream,
                       xb, wt, bias, xp, b0 * T_);
    hipLaunchKernelGGL(pred_k, dim3(256, bc), dim3(256), 0, stream,
                       xp, yT, negs, out, b0);
  }
}

// Round 2
// 223.413 us; speedup vs baseline: 1.0446x; 1.0446x over previous
//
#include <hip/hip_runtime.h>

typedef __bf16 bf16x8 __attribute__((ext_vector_type(8)));
typedef float f32x4 __attribute__((ext_vector_type(4)));

#define B_ 16
#define T_ 1024
#define D_ 512
#define S_ 12
#define C_ 11
static constexpr int P_TOTAL = 2148960;  // 176 * (12*1024 - 78)

__device__ __host__ inline constexpr int pred_base(int i) {
  return C_ * B_ * (T_ * i - (i * (i + 1)) / 2);
}

__device__ inline unsigned short f2bf(float f) {
  unsigned int u = __float_as_uint(f);
  u += 0x7FFF + ((u >> 16) & 1);   // round-to-nearest-even
  return (unsigned short)(u >> 16);
}

__device__ inline void gld16(const void* g, void* l) {
  __builtin_amdgcn_global_load_lds(
      (const __attribute__((address_space(1))) void*)g,
      (__attribute__((address_space(3))) void*)l, 16, 0, 0);
}

// ---------------- prep: W [i][o][s] f32 -> wt [s][o][i] bf16 ----------------
__global__ __launch_bounds__(256) void prep_w(const float* __restrict__ W,
                                              unsigned short* __restrict__ wt) {
  __shared__ unsigned short tile[32][33][12];
  const int i0 = blockIdx.x * 32, o0 = blockIdx.y * 32;
#pragma unroll
  for (int q = 0; q < 48; ++q) {
    int idx = threadIdx.x + q * 256;
    int ii = idx / 384, rem = idx % 384;
    tile[ii][rem / 12][rem % 12] =
        f2bf(W[(size_t)(i0 + ii) * 6144 + (size_t)o0 * 12 + rem]);
  }
  __syncthreads();
#pragma unroll
  for (int q = 0; q < 48; ++q) {
    int idx = threadIdx.x + q * 256;
    int ss = idx / 1024, rem = idx % 1024;
    int oo = rem / 32, ii = rem % 32;
    wt[(size_t)ss * (D_ * D_) + (size_t)(o0 + oo) * D_ + (i0 + ii)] = tile[ii][oo][ss];
  }
}

// ------- prep: transpose [b][D][T] f32 -> [b][T][D] bf16 (x->xb, y->yT) -----
__global__ __launch_bounds__(256) void prep_t(const float* __restrict__ in,
                                              unsigned short* __restrict__ ob) {
  __shared__ float tile[32][33];
  const int t0 = blockIdx.x * 32;
  const int d0 = blockIdx.y * 32;
  const int b = blockIdx.z;
  const float* ib = in + (size_t)b * D_ * T_;
  const int r = threadIdx.x / 32, c = threadIdx.x % 32;
#pragma unroll
  for (int p = 0; p < 4; ++p) {
    int rr = r + p * 8;
    tile[rr][c] = ib[(size_t)(d0 + rr) * T_ + t0 + c];
  }
  __syncthreads();
  unsigned short* op = ob + (size_t)b * T_ * D_;
#pragma unroll
  for (int p = 0; p < 4; ++p) {
    int rr = r + p * 8;
    op[(size_t)(t0 + rr) * D_ + d0 + c] = f2bf(tile[c][rr]);
  }
}

// ---------------- labels ----------------
__global__ void labels_k(float* __restrict__ lab) {
  int k = blockIdx.x * 256 + threadIdx.x;
  if (k >= P_TOTAL) return;
  int i = 0;
#pragma unroll
  for (int q = 1; q < 12; ++q)
    if (k >= pred_base(q)) i = q;
  int rel = k - pred_base(i);
  int len = T_ - 1 - i;
  lab[k] = (rel < B_ * len) ? 1.0f : 0.0f;
}

// ---- GEMM: xp[bl][s][t][o] = xb[m][i] * wt[s][o][i] + bias[o] --------------
// 256x256 tile, BK=32, 8 waves (2Mx4N), ring-4 LDS K-tile buffers (128 KiB),
// 2 phases per K-tile, counted vmcnt(4) (T3+T4), XOR-swizzled LDS (T2),
// setprio around MFMA clusters (T5). Prefetch distance = 2 K-tiles.
__global__ __launch_bounds__(512, 2) void gemm_xp(
    const unsigned short* __restrict__ xb,   // [nb*1024][512]
    const unsigned short* __restrict__ wt,   // [12][512 o][512 i]
    const float* __restrict__ bias,          // [512]
    unsigned short* __restrict__ xp,         // [nb][12][1024][512]
    int m0_global) {
  // ring slot (kt&3): A tile at slot*16384 (shorts), B tile at +8192.
  // A/B tile: 256 rows x 32 k bf16 = 16 KB, row stride 32 shorts (64 B).
  __shared__ unsigned short lds[65536];      // 128 KiB
  const int tid = threadIdx.x;
  const int s = blockIdx.z;
  const int n0 = blockIdx.y * 256;
  const int ml0 = blockIdx.x * 256;
  const unsigned short* Ag = xb + (size_t)(m0_global + ml0) * D_;
  const unsigned short* Bg = wt + ((size_t)s * D_ + n0) * D_;

  // stage one 16KB operand tile of K-tile kt (2 x gld16 per thread).
  // LDS dest is linear (wave-uniform base + lane*16); the k-slot swizzle is
  // applied to the GLOBAL source address (both-sides-or-neither, rule #21):
  // physical slot sc holds logical k-slot sc ^ ((row>>1)&3).
  auto stage = [&](const unsigned short* src, int kt, int regionShorts) {
#pragma unroll
    for (int h = 0; h < 2; ++h) {
      int o = tid * 16 + h * 8192;           // byte offset within 16 KB tile
      int row = o >> 6;
      int sc = (o >> 4) & 3;
      int lcol = (sc ^ ((row >> 1) & 3)) << 4;  // logical col, bytes
      gld16((const char*)src + (size_t)row * (D_ * 2) + kt * 64 + lcol,
            (char*)&lds[regionShorts] + o);
    }
  };

  const int w = tid >> 6, l = tid & 63;
  const int gm = w >> 2, gn = w & 3;         // wave tile: 128m x 64n
  const int fr = l & 15, sgrp = l >> 4;      // k-slot group 0..3

  // swizzled fragment read: logical (row, k-slot sgrp) -> physical slot
  auto rdfrag = [&](const unsigned short* base, int row) -> bf16x8 {
    int idx = row * 32 + ((sgrp ^ ((row >> 1) & 3)) << 3);
    return *(const bf16x8*)&base[idx];
  };

  f32x4 acc[2][4][4];
#pragma unroll
  for (int ms = 0; ms < 2; ++ms)
#pragma unroll
    for (int fm = 0; fm < 4; ++fm)
#pragma unroll
      for (int fn = 0; fn < 4; ++fn)
#pragma unroll
        for (int e = 0; e < 4; ++e) acc[ms][fm][fn][e] = 0.f;

  // prologue: stage K-tiles 0 and 1; land tile 0, keep tile 1 in flight.
  stage(Ag, 0, 0);
  stage(Bg, 0, 8192);
  stage(Ag, 1, 16384);
  stage(Bg, 1, 16384 + 8192);
  asm volatile("s_waitcnt vmcnt(4)" ::: "memory");
  __builtin_amdgcn_s_barrier();

  for (int kt = 0; kt < 16; ++kt) {
    const unsigned short* A_l = &lds[(kt & 3) * 16384];
    const unsigned short* B_l = A_l + 8192;
    bf16x8 afrag[4], bfrag[4];

    // ---------------- phase 0: m-sub 0 ----------------
#pragma unroll
    for (int fn = 0; fn < 4; ++fn)
      bfrag[fn] = rdfrag(B_l, gn * 64 + fn * 16 + fr);
#pragma unroll
    for (int fm = 0; fm < 4; ++fm)
      afrag[fm] = rdfrag(A_l, gm * 128 + fm * 16 + fr);
    if (kt + 2 < 16) stage(Ag, kt + 2, ((kt + 2) & 3) * 16384);
    __builtin_amdgcn_s_barrier();
    __builtin_amdgcn_s_setprio(1);
#pragma unroll
    for (int fm = 0; fm < 4; ++fm)
#pragma unroll
      for (int fn = 0; fn < 4; ++fn)
        acc[0][fm][fn] = __builtin_amdgcn_mfma_f32_16x16x32_bf16(
            afrag[fm], bfrag[fn], acc[0][fm][fn], 0, 0, 0);
    __builtin_amdgcn_s_setprio(0);
    __builtin_amdgcn_s_barrier();

    // ---------------- phase 1: m-sub 1 (b-frags reused) ----------------
#pragma unroll
    for (int fm = 0; fm < 4; ++fm)
      afrag[fm] = rdfrag(A_l, gm * 128 + 64 + fm * 16 + fr);
    if (kt + 2 < 16) stage(Bg, kt + 2, ((kt + 2) & 3) * 16384 + 8192);
    __builtin_amdgcn_s_barrier();
    __builtin_amdgcn_s_setprio(1);
#pragma unroll
    for (int fm = 0; fm < 4; ++fm)
#pragma unroll
      for (int fn = 0; fn < 4; ++fn)
        acc[1][fm][fn] = __builtin_amdgcn_mfma_f32_16x16x32_bf16(
            afrag[fm], bfrag[fn], acc[1][fm][fn], 0, 0, 0);
    __builtin_amdgcn_s_setprio(0);
    // counted vmcnt once per K-tile: keep next tile's 4 loads in flight.
    if (kt <= 13) {
      asm volatile("s_waitcnt vmcnt(4)" ::: "memory");
    } else if (kt == 14) {
      asm volatile("s_waitcnt vmcnt(0)" ::: "memory");
    }
    __builtin_amdgcn_s_barrier();
  }

  // epilogue: bias + bf16 store
  float bv[4];
#pragma unroll
  for (int fn = 0; fn < 4; ++fn) bv[fn] = bias[n0 + gn * 64 + fn * 16 + fr];

#pragma unroll
  for (int ms = 0; ms < 2; ++ms) {
#pragma unroll
    for (int fm = 0; fm < 4; ++fm) {
#pragma unroll
      for (int r = 0; r < 4; ++r) {
        int m = ml0 + gm * 128 + ms * 64 + fm * 16 + (l >> 4) * 4 + r;
        int bl = m >> 10, t = m & 1023;
        size_t orow = (((size_t)bl * S_ + s) * T_ + t) * D_;
#pragma unroll
        for (int fn = 0; fn < 4; ++fn) {
          int o = n0 + gn * 64 + fn * 16 + fr;
          xp[orow + o] = f2bf(acc[ms][fm][fn][r] + bv[fn]);
        }
      }
    }
  }
}

// ---- predictions: one wave per (b, tt); 12x11 tile of dots via 16 MFMAs ----
__global__ __launch_bounds__(256) void pred_k(
    const unsigned short* __restrict__ xp,   // [nb][12][1024][512]
    const unsigned short* __restrict__ yT,   // [16][1024][512]
    const int* __restrict__ negs,            // [16][10][1024]
    float* __restrict__ preds, int b0) {
  const int w = threadIdx.x >> 6, l = threadIdx.x & 63;
  const int tt = blockIdx.x * 4 + w;
  const int bl = blockIdx.y;
  const int b = b0 + bl;
  if (tt < 1 || tt >= T_) return;

  const int fr = l & 15;
  const int koff = (l >> 4) * 8;

  int t = tt - 1 - fr;
  bool av = (fr < S_) && (t >= 0);
  int si = av ? fr : 0;
  int st = av ? t : 0;
  const unsigned short* arow = xp + (((size_t)bl * S_ + si) * T_ + st) * D_;

  int j = tt;
  if (fr >= 1 && fr <= 10) j = negs[b * (10 * T_) + (fr - 1) * T_ + tt];
  const unsigned short* brow = yT + ((size_t)b * T_ + j) * D_;

  f32x4 acc;
#pragma unroll
  for (int e = 0; e < 4; ++e) acc[e] = 0.f;
#pragma unroll
  for (int kk = 0; kk < 16; ++kk) {
    bf16x8 a = *(const bf16x8*)(arow + kk * 32 + koff);
    bf16x8 bb = *(const bf16x8*)(brow + kk * 32 + koff);
    acc = __builtin_amdgcn_mfma_f32_16x16x32_bf16(a, bb, acc, 0, 0, 0);
  }
#pragma unroll
  for (int r = 0; r < 4; ++r) {
    int ii = (l >> 4) * 4 + r;
    int to = tt - 1 - ii;
    if (ii < S_ && fr < C_ && to >= 0) {
      int len = T_ - 1 - ii;
      preds[pred_base(ii) + ((size_t)fr * B_ + b) * len + to] = acc[r];
    }
  }
}

extern "C" void kernel_launch(void* const* d_in, const int* in_sizes, int n_in,
                              void* d_out, int out_size, void* d_ws, size_t ws_size,
                              hipStream_t stream) {
  (void)in_sizes; (void)n_in; (void)out_size;
  const float* x = (const float*)d_in[0];
  const float* y = (const float*)d_in[1];
  const float* W = (const float*)d_in[2];
  const float* bias = (const float*)d_in[3];
  const int* negs = (const int*)d_in[4];
  float* out = (float*)d_out;
  char* ws = (char*)d_ws;

  unsigned short* wt = (unsigned short*)ws;                         // 6,291,456 B
  unsigned short* xb = (unsigned short*)(ws + 6291456);             // 16,777,216 B
  unsigned short* yT = (unsigned short*)(ws + 6291456 + 16777216);  // 16,777,216 B
  unsigned short* xp = (unsigned short*)(ws + 6291456 + 2 * 16777216);
  const size_t fixed = 6291456 + (size_t)2 * 16777216;              // 39,845,888
  const size_t xp_per_b = (size_t)S_ * T_ * D_ * 2;                 // 12,582,912
  int nb = 1;
  if (ws_size > fixed) {
    size_t cap = (ws_size - fixed) / xp_per_b;
    nb = cap < 1 ? 1 : (cap > 16 ? 16 : (int)cap);
  }

  hipLaunchKernelGGL(prep_w, dim3(16, 16), dim3(256), 0, stream, W, wt);
  hipLaunchKernelGGL(prep_t, dim3(32, 16, 16), dim3(256), 0, stream, x, xb);
  hipLaunchKernelGGL(prep_t, dim3(32, 16, 16), dim3(256), 0, stream, y, yT);
  hipLaunchKernelGGL(labels_k, dim3((P_TOTAL + 255) / 256), dim3(256), 0, stream,
                     out + P_TOTAL);

  for (int b0 = 0; b0 < B_; b0 += nb) {
    int bc = (B_ - b0) < nb ? (B_ - b0) : nb;
    // 256-row m-tiles over bc*1024 rows; 2 n-tiles per s; 12 s.
    hipLaunchKernelGGL(gemm_xp, dim3(bc * 4, 2, 12), dim3(512), 0, stream,
                       xb, wt, bias, xp, b0 * T_);
    hipLaunchKernelGGL(pred_k, dim3(256, bc), dim3(256), 0, stream,
                       xp, yT, negs, out, b0);
  }
}

// Round 3
// 216.304 us; speedup vs baseline: 1.0790x; 1.0329x over previous
//
#include <hip/hip_runtime.h>

typedef __bf16 bf16x8 __attribute__((ext_vector_type(8)));
typedef float f32x4 __attribute__((ext_vector_type(4)));

#define B_ 16
#define T_ 1024
#define D_ 512
#define S_ 12
#define C_ 11
static constexpr int P_TOTAL = 2148960;  // 176 * (12*1024 - 78)

__device__ __host__ inline constexpr int pred_base(int i) {
  return C_ * B_ * (T_ * i - (i * (i + 1)) / 2);
}

__device__ inline unsigned short f2bf(float f) {
  unsigned int u = __float_as_uint(f);
  u += 0x7FFF + ((u >> 16) & 1);   // round-to-nearest-even
  return (unsigned short)(u >> 16);
}

__device__ inline void gld16(const void* g, void* l) {
  __builtin_amdgcn_global_load_lds(
      (const __attribute__((address_space(1))) void*)g,
      (__attribute__((address_space(3))) void*)l, 16, 0, 0);
}

// ---------------- prep: W [i][o][s] f32 -> wt [s][o][i] bf16 ----------------
__global__ __launch_bounds__(256) void prep_w(const float* __restrict__ W,
                                              unsigned short* __restrict__ wt) {
  __shared__ unsigned short tile[32][33][12];
  const int i0 = blockIdx.x * 32, o0 = blockIdx.y * 32;
#pragma unroll
  for (int q = 0; q < 48; ++q) {
    int idx = threadIdx.x + q * 256;
    int ii = idx / 384, rem = idx % 384;
    tile[ii][rem / 12][rem % 12] =
        f2bf(W[(size_t)(i0 + ii) * 6144 + (size_t)o0 * 12 + rem]);
  }
  __syncthreads();
#pragma unroll
  for (int q = 0; q < 48; ++q) {
    int idx = threadIdx.x + q * 256;
    int ss = idx / 1024, rem = idx % 1024;
    int oo = rem / 32, ii = rem % 32;
    wt[(size_t)ss * (D_ * D_) + (size_t)(o0 + oo) * D_ + (i0 + ii)] = tile[ii][oo][ss];
  }
}

// -- prep: transpose [b][D][T] f32 -> [b][T][D] bf16, both x and y (z=0..31) --
__global__ __launch_bounds__(256) void prep_t2(const float* __restrict__ xin,
                                               const float* __restrict__ yin,
                                               unsigned short* __restrict__ xo,
                                               unsigned short* __restrict__ yo) {
  __shared__ float tile[32][33];
  const int t0 = blockIdx.x * 32;
  const int d0 = blockIdx.y * 32;
  const int b = blockIdx.z & 15;
  const float* in = (blockIdx.z < 16) ? xin : yin;
  unsigned short* ob = (blockIdx.z < 16) ? xo : yo;
  const float* ib = in + (size_t)b * D_ * T_;
  const int r = threadIdx.x / 32, c = threadIdx.x % 32;
#pragma unroll
  for (int p = 0; p < 4; ++p) {
    int rr = r + p * 8;
    tile[rr][c] = ib[(size_t)(d0 + rr) * T_ + t0 + c];
  }
  __syncthreads();
  unsigned short* op = ob + (size_t)b * T_ * D_;
#pragma unroll
  for (int p = 0; p < 4; ++p) {
    int rr = r + p * 8;
    op[(size_t)(t0 + rr) * D_ + d0 + c] = f2bf(tile[c][rr]);
  }
}

// ---------------- labels ----------------
__global__ void labels_k(float* __restrict__ lab) {
  int k = blockIdx.x * 256 + threadIdx.x;
  if (k >= P_TOTAL) return;
  int i = 0;
#pragma unroll
  for (int q = 1; q < 12; ++q)
    if (k >= pred_base(q)) i = q;
  int rel = k - pred_base(i);
  int len = T_ - 1 - i;
  lab[k] = (rel < B_ * len) ? 1.0f : 0.0f;
}

// ---- GEMM: xp[bl][s][t][o] = xb[m][i] * wt[s][o][i] + bias[o] --------------
// Persistent blocks: each block processes tiles {bid, bid+G, ...} sharing one
// A-panel. 256x256 tile, BK=32, 8 waves, ring-4 LDS (128 KiB), one barrier per
// phase, counted vmcnt(4) once per K-tile, continuous staging across tiles.
__global__ __launch_bounds__(512, 2) void gemm_xp(
    const unsigned short* __restrict__ xb,   // [bc*1024][512]
    const unsigned short* __restrict__ wt,   // [12][512 o][512 i]
    const float* __restrict__ bias,          // [512]
    unsigned short* __restrict__ xp,         // [bc][12][1024][512]
    int m0_global, int tiles, int mtiles) {
  __shared__ unsigned short lds[65536];      // 4 slots x (A 8192 + B 8192) shorts
  const int tid = threadIdx.x;
  const int w = tid >> 6, l = tid & 63;
  const int gm = w >> 2, gn = w & 3;         // wave tile: 128m x 64n
  const int fr = l & 15, sgrp = l >> 4;

  // staging constants: 2 x gld16 per 16KB operand tile; source column swizzled
  // (rule #21: LDS dest linear, inverse swizzle on global source).
  const int so0 = tid * 16;                  // byte offset in 16KB tile
  const int row0 = so0 >> 6, sc0 = (so0 >> 4) & 3;
  const int go0 = row0 * 1024 + ((sc0 ^ ((row0 >> 1) & 3)) << 4);
  const int so1 = so0 + 8192;
  const int row1 = so1 >> 6, sc1 = (so1 >> 4) & 3;
  const int go1 = row1 * 1024 + ((sc1 ^ ((row1 >> 1) & 3)) << 4);

  auto stage = [&](const unsigned short* srcKt, int slotShorts) {
    gld16((const char*)srcKt + go0, (char*)&lds[slotShorts] + so0);
    gld16((const char*)srcKt + go1, (char*)&lds[slotShorts] + so1);
  };

  auto rdfrag = [&](const unsigned short* base, int row) -> bf16x8 {
    int idx = row * 32 + ((sgrp ^ ((row >> 1) & 3)) << 3);
    return *(const bf16x8*)&base[idx];
  };

  auto decode = [&](int t, const unsigned short*& Ag, const unsigned short*& Bg,
                    int& n0v, int& miv, int& siv) {
    miv = t % mtiles;
    int rest = t / mtiles;
    int ni = rest & 1;
    siv = rest >> 1;
    Ag = xb + (size_t)(miv * 256) * D_;
    Bg = wt + ((size_t)siv * D_ + ni * 256) * D_;
    n0v = ni * 256;
  };
  (void)m0_global;

  int ti = blockIdx.x;
  if (ti >= tiles) return;
  const unsigned short *Ag, *Bg, *Agn = nullptr, *Bgn = nullptr;
  int n0, mi, si, n0n, min_, sin_;
  decode(ti, Ag, Bg, n0, mi, si);
  int tin = ti + gridDim.x;
  bool hasNext = tin < tiles;
  if (hasNext) decode(tin, Agn, Bgn, n0n, min_, sin_);

  // prologue: K-tiles 0,1 of first tile
  stage(Ag, 0);
  stage(Bg, 8192);
  stage(Ag + 32, 16384);
  stage(Bg + 32, 16384 + 8192);
  asm volatile("s_waitcnt vmcnt(4)" ::: "memory");
  __builtin_amdgcn_s_barrier();

  while (true) {
    f32x4 acc[2][4][4];
#pragma unroll
    for (int ms = 0; ms < 2; ++ms)
#pragma unroll
      for (int fm = 0; fm < 4; ++fm)
#pragma unroll
        for (int fn = 0; fn < 4; ++fn)
#pragma unroll
          for (int e = 0; e < 4; ++e) acc[ms][fm][fn][e] = 0.f;

    float bv[4];
#pragma unroll
    for (int fn = 0; fn < 4; ++fn) bv[fn] = bias[n0 + gn * 64 + fn * 16 + fr];

    for (int kt = 0; kt < 16; ++kt) {
      const int sl = kt & 3;
      const unsigned short* A_l = &lds[sl * 16384];
      const unsigned short* B_l = A_l + 8192;
      const int k2 = kt + 2;
      const int sl2s = (k2 & 3) * 16384;
      const unsigned short* sA = nullptr;
      const unsigned short* sB = nullptr;
      if (k2 < 16) {
        sA = Ag + k2 * 32;
        sB = Bg + k2 * 32;
      } else if (hasNext) {
        sA = Agn + (k2 - 16) * 32;
        sB = Bgn + (k2 - 16) * 32;
      }
      bf16x8 af[4], bfr[4];

      // ---- phase 0: m-sub 0 ----
#pragma unroll
      for (int fn = 0; fn < 4; ++fn)
        bfr[fn] = rdfrag(B_l, gn * 64 + fn * 16 + fr);
#pragma unroll
      for (int fm = 0; fm < 4; ++fm)
        af[fm] = rdfrag(A_l, gm * 128 + fm * 16 + fr);
      if (sA) stage(sA, sl2s);
      __builtin_amdgcn_s_barrier();
      __builtin_amdgcn_s_setprio(1);
#pragma unroll
      for (int fm = 0; fm < 4; ++fm)
#pragma unroll
        for (int fn = 0; fn < 4; ++fn)
          acc[0][fm][fn] = __builtin_amdgcn_mfma_f32_16x16x32_bf16(
              af[fm], bfr[fn], acc[0][fm][fn], 0, 0, 0);
      __builtin_amdgcn_s_setprio(0);

      // ---- phase 1: m-sub 1 (b-frags reused) ----
#pragma unroll
      for (int fm = 0; fm < 4; ++fm)
        af[fm] = rdfrag(A_l, gm * 128 + 64 + fm * 16 + fr);
      if (sB) stage(sB, sl2s + 8192);
      asm volatile("s_waitcnt vmcnt(4)" ::: "memory");
      __builtin_amdgcn_s_barrier();
      __builtin_amdgcn_s_setprio(1);
#pragma unroll
      for (int fm = 0; fm < 4; ++fm)
#pragma unroll
        for (int fn = 0; fn < 4; ++fn)
          acc[1][fm][fn] = __builtin_amdgcn_mfma_f32_16x16x32_bf16(
              af[fm], bfr[fn], acc[1][fm][fn], 0, 0, 0);
      __builtin_amdgcn_s_setprio(0);
    }

    // epilogue: bias + bf16 store (overlaps next tile's in-flight stages)
#pragma unroll
    for (int ms = 0; ms < 2; ++ms) {
#pragma unroll
      for (int fm = 0; fm < 4; ++fm) {
#pragma unroll
        for (int r = 0; r < 4; ++r) {
          int m = mi * 256 + gm * 128 + ms * 64 + fm * 16 + sgrp * 4 + r;
          int bl = m >> 10, t = m & 1023;
          size_t orow = (((size_t)bl * S_ + si) * T_ + t) * D_;
#pragma unroll
          for (int fn = 0; fn < 4; ++fn) {
            int o = n0 + gn * 64 + fn * 16 + fr;
            xp[orow + o] = f2bf(acc[ms][fm][fn][r] + bv[fn]);
          }
        }
      }
    }

    if (!hasNext) break;
    ti = tin;
    Ag = Agn; Bg = Bgn; n0 = n0n; mi = min_; si = sin_;
    tin = ti + gridDim.x;
    hasNext = tin < tiles;
    if (hasNext) decode(tin, Agn, Bgn, n0n, min_, sin_);
  }
}

// ---- predictions: one wave per (b, 2 x tt); 12x11 tiles via 16 MFMAs each --
__global__ __launch_bounds__(256) void pred_k(
    const unsigned short* __restrict__ xp,   // [bc][12][1024][512]
    const unsigned short* __restrict__ yT,   // [16][1024][512]
    const int* __restrict__ negs,            // [16][10][1024]
    float* __restrict__ preds, int b0) {
  const int w = threadIdx.x >> 6, l = threadIdx.x & 63;
  const int bl = blockIdx.y;
  const int b = b0 + bl;
  const int fr = l & 15;
  const int koff = (l >> 4) * 8;
  const int tta = blockIdx.x * 4 + w;        // 0..511
  const int ttb = tta + 512;                 // 512..1023

  // A rows (i = fr), clamped to safe addresses when invalid
  int ta = tta - 1 - fr;
  bool ava = (fr < S_) && (ta >= 0);
  const unsigned short* arowA =
      xp + (((size_t)bl * S_ + (ava ? fr : 0)) * T_ + (ava ? ta : 0)) * D_;
  int tb = ttb - 1 - fr;
  bool avb = (fr < S_) && (tb >= 0);
  const unsigned short* arowB =
      xp + (((size_t)bl * S_ + (avb ? fr : 0)) * T_ + (avb ? tb : 0)) * D_;

  // B cols (c = fr): pos column tt, negs for c=1..10
  int ja = tta, jb = ttb;
  if (fr >= 1 && fr <= 10) {
    ja = negs[b * (10 * T_) + (fr - 1) * T_ + tta];
    jb = negs[b * (10 * T_) + (fr - 1) * T_ + ttb];
  }
  const unsigned short* browA = yT + ((size_t)b * T_ + ja) * D_;
  const unsigned short* browB = yT + ((size_t)b * T_ + jb) * D_;

  f32x4 accA, accB;
#pragma unroll
  for (int e = 0; e < 4; ++e) { accA[e] = 0.f; accB[e] = 0.f; }
#pragma unroll
  for (int kk = 0; kk < 16; ++kk) {
    bf16x8 a0 = *(const bf16x8*)(arowA + kk * 32 + koff);
    bf16x8 b0v = *(const bf16x8*)(browA + kk * 32 + koff);
    bf16x8 a1 = *(const bf16x8*)(arowB + kk * 32 + koff);
    bf16x8 b1v = *(const bf16x8*)(browB + kk * 32 + koff);
    accA = __builtin_amdgcn_mfma_f32_16x16x32_bf16(a0, b0v, accA, 0, 0, 0);
    accB = __builtin_amdgcn_mfma_f32_16x16x32_bf16(a1, b1v, accB, 0, 0, 0);
  }
#pragma unroll
  for (int r = 0; r < 4; ++r) {
    int ii = (l >> 4) * 4 + r;
    if (ii < S_ && fr < C_) {
      int len = T_ - 1 - ii;
      int toa = tta - 1 - ii;
      if (tta >= 1 && toa >= 0)
        preds[pred_base(ii) + ((size_t)fr * B_ + b) * len + toa] = accA[r];
      int tob = ttb - 1 - ii;
      if (tob >= 0)
        preds[pred_base(ii) + ((size_t)fr * B_ + b) * len + tob] = accB[r];
    }
  }
}

extern "C" void kernel_launch(void* const* d_in, const int* in_sizes, int n_in,
                              void* d_out, int out_size, void* d_ws, size_t ws_size,
                              hipStream_t stream) {
  (void)in_sizes; (void)n_in; (void)out_size;
  const float* x = (const float*)d_in[0];
  const float* y = (const float*)d_in[1];
  const float* W = (const float*)d_in[2];
  const float* bias = (const float*)d_in[3];
  const int* negs = (const int*)d_in[4];
  float* out = (float*)d_out;
  char* ws = (char*)d_ws;

  unsigned short* wt = (unsigned short*)ws;                         // 6,291,456 B
  unsigned short* xb = (unsigned short*)(ws + 6291456);             // 16,777,216 B
  unsigned short* yT = (unsigned short*)(ws + 6291456 + 16777216);  // 16,777,216 B
  unsigned short* xp = (unsigned short*)(ws + 6291456 + 2 * 16777216);
  const size_t fixed = 6291456 + (size_t)2 * 16777216;              // 39,845,888
  const size_t xp_per_b = (size_t)S_ * T_ * D_ * 2;                 // 12,582,912
  int nb = 1;
  if (ws_size > fixed) {
    size_t cap = (ws_size - fixed) / xp_per_b;
    nb = cap < 1 ? 1 : (cap > 16 ? 16 : (int)cap);
  }

  hipLaunchKernelGGL(prep_w, dim3(16, 16), dim3(256), 0, stream, W, wt);
  hipLaunchKernelGGL(prep_t2, dim3(32, 16, 32), dim3(256), 0, stream, x, y, xb, yT);
  hipLaunchKernelGGL(labels_k, dim3((P_TOTAL + 255) / 256), dim3(256), 0, stream,
                     out + P_TOTAL);

  for (int b0 = 0; b0 < B_; b0 += nb) {
    int bc = (B_ - b0) < nb ? (B_ - b0) : nb;
    int tiles = bc * 4 * 2 * 12;
    int grid = tiles < 256 ? tiles : 256;
    hipLaunchKernelGGL(gemm_xp, dim3(grid), dim3(512), 0, stream,
                       xb + (size_t)b0 * T_ * D_, wt, bias, xp, b0 * T_,
                       tiles, bc * 4);
    hipLaunchKernelGGL(pred_k, dim3(128, bc), dim3(256), 0, stream,
                       xp, yT, negs, out, b0);
  }
}